// Round 3
// baseline (589.070 us; speedup 1.0000x reference)
//
#include <hip/hip_runtime.h>
#include <hip/hip_bf16.h>

typedef float  f32x4  __attribute__((ext_vector_type(4)));
typedef __bf16 bf16x8 __attribute__((ext_vector_type(8)));
typedef short  s16x8  __attribute__((ext_vector_type(8)));
typedef short  s16x4  __attribute__((ext_vector_type(4)));

// fp32 -> bf16 round-to-nearest-even (raw bits in short)
__device__ __forceinline__ short f2b(float f) {
  unsigned u = __builtin_bit_cast(unsigned, f);
  u = (u + 0x7fffu + ((u >> 16) & 1u)) >> 16;
  return (short)u;
}
// bf16 bits -> fp32 (exact)
__device__ __forceinline__ float b2f(short s) {
  unsigned u = ((unsigned)(unsigned short)s) << 16;
  return __builtin_bit_cast(float, u);
}

// 8 fp32 -> bf16x8 via packed cvt (v_cvt_pk_bf16_f32 on gfx950)
__device__ __forceinline__ bf16x8 pack8(f32x4 a, f32x4 b) {
  union { bf16x8 v; __hip_bfloat162 h[4]; } u;
  u.h[0] = __float22bfloat162_rn(make_float2(a[0], a[1]));
  u.h[1] = __float22bfloat162_rn(make_float2(a[2], a[3]));
  u.h[2] = __float22bfloat162_rn(make_float2(b[0], b[1]));
  u.h[3] = __float22bfloat162_rn(make_float2(b[2], b[3]));
  return u.v;
}

// W [2][256 c][256 d] fp32  ->  Wt [2][256 d][256 c] bf16 (B-operand friendly)
__global__ void prep_wt(const float* __restrict__ W, short* __restrict__ Wt) {
  int q = blockIdx.x * blockDim.x + threadIdx.x;   // 0..32767, each handles 4 elems
  int mat = q >> 14;
  int rem = q & 16383;
  int d   = rem >> 6;
  int c4  = (rem & 63) << 2;
  const float* src = W + mat * 65536;
  s16x4 o;
  #pragma unroll
  for (int i = 0; i < 4; ++i) o[i] = f2b(src[(c4 + i) * 256 + d]);
  *(s16x4*)&Wt[q << 2] = o;   // flat = mat*65536 + d*256 + c4
}

// R3: barrier-free K-loop with direct global->register MFMA fragments.
//  - A-frag (16x16x32): lane holds x[row=m16][k=qd*8..+8] = 32 contiguous bytes -> 2x f32x4 direct load + pk-cvt.
//  - B-frag: 16 contiguous bytes of Wt[d][c] -> direct load (Wt 256KB, L2-resident).
//  - Tile: 4 batches = 68 rows (pad to 80 = 5 rowfrags) x 128 d. acc[5][4] = 80 regs
//    so total unified regs ~190 -> 2 waves/SIMD (R2's acc[9][4]=144 pushed unified
//    file to ~350 -> 1 wave/SIMD -> 11.8% occupancy, gang-stalled barriers).
//  - LDS only in epilogue (37KB), 2 barriers/block total.
__global__ __launch_bounds__(256, 2)
void fused_mgc(const float* __restrict__ x, const short* __restrict__ Wt,
               const float* __restrict__ M, const float* __restrict__ adj,
               const float* __restrict__ adj2, const float* __restrict__ bias,
               float* __restrict__ out) {
  __shared__ short sbuf[68 * 132];   // diag_i*M*h0, bf16
  __shared__ short gbuf[68 * 132];   // M*h1, bf16
  __shared__ float aoff[289];        // symmetrized A, diagonal zeroed
  __shared__ float diagl[17];        // diag of A

  const int tid  = threadIdx.x;
  const int lane = tid & 63;
  const int wv   = tid >> 6;
  const int m16  = lane & 15;
  const int qd   = lane >> 4;

  const int bt = blockIdx.x >> 1;  // batch tile: rows bt*68 .. +68 (68 = 4*17)
  const int ct = blockIdx.x & 1;   // col tile (128 d); ct fast => L3 reuse of x

  for (int idx = tid; idx < 289; idx += 256) {
    int i = idx / 17, j = idx - i * 17;
    float v = 0.5f * ((adj[i*17+j] + adj2[i*17+j]) + (adj[j*17+i] + adj2[j*17+i]));
    aoff[idx] = (i == j) ? 0.0f : v;
    if (i == j) diagl[i] = adj[i*17+i] + adj2[i*17+i];
  }

  f32x4 acc[5][4];  // [rowfrag][mat*2+colfrag]
  #pragma unroll
  for (int a = 0; a < 5; ++a)
    #pragma unroll
    for (int b = 0; b < 4; ++b) acc[a][b] = (f32x4)0.0f;

  const float* xbase = x + (size_t)bt * 68 * 256;
  const short* wbase = Wt + (ct * 128 + wv * 32 + m16) * 256;  // + mat*65536 + cf*16*256

  #pragma unroll
  for (int kc = 0; kc < 4; ++kc) {
    #pragma unroll
    for (int ks = 0; ks < 2; ++ks) {
      const int kq = kc * 64 + ks * 32 + qd * 8;
      // A fragments: direct from global (rows clamped; pad rows produce garbage
      // C-rows 68..79 that are never stored)
      bf16x8 af[5];
      #pragma unroll
      for (int rf = 0; rf < 5; ++rf) {
        int row = rf * 16 + m16;
        row = row < 68 ? row : 67;
        const float* p = xbase + row * 256 + kq;
        f32x4 lo = *(const f32x4*)p;
        f32x4 hi = *(const f32x4*)(p + 4);
        af[rf] = pack8(lo, hi);
      }
      // B fragments: direct from global Wt (L2-hit)
      bf16x8 bfr[4];
      #pragma unroll
      for (int mc = 0; mc < 4; ++mc) {
        int mat = mc >> 1, cf = mc & 1;
        s16x8 t = *(const s16x8*)&wbase[mat * 65536 + cf * 16 * 256 + kq];
        bfr[mc] = __builtin_bit_cast(bf16x8, t);
      }
      #pragma unroll
      for (int rf = 0; rf < 5; ++rf)
        #pragma unroll
        for (int mc = 0; mc < 4; ++mc)
          acc[rf][mc] = __builtin_amdgcn_mfma_f32_16x16x32_bf16(af[rf], bfr[mc], acc[rf][mc], 0, 0, 0);
    }
  }

  __syncthreads();   // aoff/diagl visible; epilogue starts
  // phase 1: registers (C-layout: col=lane&15, row=(lane>>4)*4+reg) -> LDS as bf16
  #pragma unroll
  for (int rf = 0; rf < 5; ++rf) {
    #pragma unroll
    for (int cf = 0; cf < 2; ++cf) {
      int c = wv * 32 + cf * 16 + m16;
      #pragma unroll
      for (int reg = 0; reg < 4; ++reg) {
        int r = rf * 16 + qd * 4 + reg;
        if (r < 68) {
          int n = r % 17;
          float mv = M[n * 256 + ct * 128 + c];
          sbuf[r * 132 + c] = f2b(diagl[n] * mv * acc[rf][cf][reg]);
          gbuf[r * 132 + c] = f2b(mv * acc[rf][2 + cf][reg]);
        }
      }
    }
  }
  __syncthreads();
  // phase 2: mixing. i,j uniform across threads -> aoff reads are broadcasts.
  const int d7   = tid & 127;
  const int half = tid >> 7;
  const float bi = bias[ct * 128 + d7];
  for (int gg = 0; gg < 2; ++gg) {
    int g = half * 2 + gg;           // batch-group within tile (0..3)
    int rbase = g * 17;
    float gr[17];
    #pragma unroll
    for (int j = 0; j < 17; ++j) gr[j] = b2f(gbuf[(rbase + j) * 132 + d7]);
    #pragma unroll
    for (int i = 0; i < 17; ++i) {
      float s = b2f(sbuf[(rbase + i) * 132 + d7]) + bi;
      #pragma unroll
      for (int j = 0; j < 17; ++j) s += aoff[i * 17 + j] * gr[j];
      out[((bt * 4 + g) * 17 + i) * 256 + ct * 128 + d7] = s;
    }
  }
}

extern "C" void kernel_launch(void* const* d_in, const int* in_sizes, int n_in,
                              void* d_out, int out_size, void* d_ws, size_t ws_size,
                              hipStream_t stream) {
  const float* x    = (const float*)d_in[0];
  const float* W    = (const float*)d_in[1];
  const float* M    = (const float*)d_in[2];
  const float* adj  = (const float*)d_in[3];
  const float* adj2 = (const float*)d_in[4];
  const float* bias = (const float*)d_in[5];
  float* out = (float*)d_out;
  short* Wt  = (short*)d_ws;   // 262144 B scratch for transposed bf16 weights

  prep_wt<<<128, 256, 0, stream>>>(W, Wt);
  fused_mgc<<<4096, 256, 0, stream>>>(x, Wt, M, adj, adj2, bias, out);
}

// Round 4
// 458.905 us; speedup vs baseline: 1.2836x; 1.2836x over previous
//
#include <hip/hip_runtime.h>
#include <hip/hip_bf16.h>

typedef float  f32x4  __attribute__((ext_vector_type(4)));
typedef __bf16 bf16x8 __attribute__((ext_vector_type(8)));
typedef short  s16x8  __attribute__((ext_vector_type(8)));
typedef short  s16x4  __attribute__((ext_vector_type(4)));

// fp32 -> bf16 round-to-nearest-even (raw bits in short)
__device__ __forceinline__ short f2b(float f) {
  unsigned u = __builtin_bit_cast(unsigned, f);
  u = (u + 0x7fffu + ((u >> 16) & 1u)) >> 16;
  return (short)u;
}
// bf16 bits -> fp32 (exact)
__device__ __forceinline__ float b2f(short s) {
  unsigned u = ((unsigned)(unsigned short)s) << 16;
  return __builtin_bit_cast(float, u);
}
// 4 fp32 -> 4 bf16 (packed cvt)
__device__ __forceinline__ s16x4 pack4(f32x4 a) {
  union { s16x4 v; __hip_bfloat162 h[2]; } u;
  u.h[0] = __float22bfloat162_rn(make_float2(a[0], a[1]));
  u.h[1] = __float22bfloat162_rn(make_float2(a[2], a[3]));
  return u.v;
}

// W [2][256 c][256 d] fp32  ->  Wt [2][256 d][256 c] bf16 (B-operand friendly)
__global__ void prep_wt(const float* __restrict__ W, short* __restrict__ Wt) {
  int q = blockIdx.x * blockDim.x + threadIdx.x;   // 0..32767, each handles 4 elems
  int mat = q >> 14;
  int rem = q & 16383;
  int d   = rem >> 6;
  int c4  = (rem & 63) << 2;
  const float* src = W + mat * 65536;
  s16x4 o;
  #pragma unroll
  for (int i = 0; i < 4; ++i) o[i] = f2b(src[(c4 + i) * 256 + d]);
  *(s16x4*)&Wt[q << 2] = o;   // flat = mat*65536 + d*256 + c4
}

// R4 = R2's LDS staging (spill-free) + R3's small tile (2 waves/SIMD):
//  - Stage whole 68x256 x-tile to LDS bf16 up-front: 17 independent f32x4
//    loads/thread in one burst (MLP), then K-loop is ds_read + L2-resident W + MFMA.
//  - acc[5][4] = 80 AGPR; K-loop VGPR ~90 -> fits the (256,2) 128/128 split. R3
//    spilled because 10 in-flight global A-loads + pipelining blew the cap;
//    LDS staging removes that set from the loop.
//  - LDS union: xs[68][264] shorts == sbuf+gbuf (both 17952 shorts = 35.9KB).
__global__ __launch_bounds__(256, 2)
void fused_mgc(const float* __restrict__ x, const short* __restrict__ Wt,
               const float* __restrict__ M, const float* __restrict__ adj,
               const float* __restrict__ adj2, const float* __restrict__ bias,
               float* __restrict__ out) {
  __shared__ short smem[17952];   // xs[68][264] | union | sbuf[68][132]+gbuf[68][132]
  __shared__ float aoff[289];     // symmetrized A, diagonal zeroed
  __shared__ float diagl[17];     // diag of A

  const int tid  = threadIdx.x;
  const int lane = tid & 63;
  const int wv   = tid >> 6;
  const int m16  = lane & 15;
  const int qd   = lane >> 4;

  const int bt = blockIdx.x >> 1;  // batch tile: rows bt*68 .. +68 (68 = 4*17)
  const int ct = blockIdx.x & 1;   // col tile (128 d); ct fast => L2 reuse of x

  for (int idx = tid; idx < 289; idx += 256) {
    int i = idx / 17, j = idx - i * 17;
    float v = 0.5f * ((adj[i*17+j] + adj2[i*17+j]) + (adj[j*17+i] + adj2[j*17+i]));
    aoff[idx] = (i == j) ? 0.0f : v;
    if (i == j) diagl[i] = adj[i*17+i] + adj2[i*17+i];
  }

  // ---- stage x tile: 68 rows x 256 k, fp32 -> bf16 LDS (stride 264 shorts) ----
  {
    const float* xbase = x + (size_t)bt * 68 * 256;
    const int c4 = (tid & 63) << 2;   // col quad: 64 quads = 256 cols = 1 row/wave-op
    const int r0 = tid >> 6;          // 0..3
    #pragma unroll
    for (int it = 0; it < 17; ++it) {
      int row = r0 + it * 4;
      f32x4 v = *(const f32x4*)&xbase[row * 256 + c4];
      *(s16x4*)&smem[row * 264 + c4] = pack4(v);
    }
  }

  f32x4 acc[5][4];  // [rowfrag][mat*2+colfrag]
  #pragma unroll
  for (int a = 0; a < 5; ++a)
    #pragma unroll
    for (int b = 0; b < 4; ++b) acc[a][b] = (f32x4)0.0f;

  const short* wbase = Wt + (ct * 128 + wv * 32 + m16) * 256;  // + mat*65536 + cf*4096

  __syncthreads();   // xs ready

  // A-row indices (clamped: rows 68..79 read row 67; their C-rows are never stored)
  int arow[5];
  #pragma unroll
  for (int rf = 0; rf < 5; ++rf) {
    int r = rf * 16 + m16;
    arow[rf] = (r < 68 ? r : 67) * 264;
  }

  #pragma unroll
  for (int ks = 0; ks < 8; ++ks) {
    const int kq = ks * 32 + qd * 8;
    bf16x8 bfr[4];
    #pragma unroll
    for (int mc = 0; mc < 4; ++mc) {
      int mat = mc >> 1, cf = mc & 1;
      s16x8 t = *(const s16x8*)&wbase[mat * 65536 + cf * 4096 + kq];
      bfr[mc] = __builtin_bit_cast(bf16x8, t);
    }
    #pragma unroll
    for (int rf = 0; rf < 5; ++rf) {
      s16x8 t = *(const s16x8*)&smem[arow[rf] + kq];
      bf16x8 af = __builtin_bit_cast(bf16x8, t);
      #pragma unroll
      for (int mc = 0; mc < 4; ++mc)
        acc[rf][mc] = __builtin_amdgcn_mfma_f32_16x16x32_bf16(af, bfr[mc], acc[rf][mc], 0, 0, 0);
    }
  }

  __syncthreads();   // all waves done reading xs; reuse smem for epilogue
  short* sbuf = smem;          // [68][132] bf16: diag_i*M*h0
  short* gbuf = smem + 8976;   // [68][132] bf16: M*h1

  // phase 1: registers (C-layout: col=lane&15, row=(lane>>4)*4+reg) -> LDS as bf16
  #pragma unroll
  for (int rf = 0; rf < 5; ++rf) {
    #pragma unroll
    for (int cf = 0; cf < 2; ++cf) {
      int c = wv * 32 + cf * 16 + m16;
      #pragma unroll
      for (int reg = 0; reg < 4; ++reg) {
        int r = rf * 16 + qd * 4 + reg;
        if (r < 68) {
          int n = r % 17;
          float mv = M[n * 256 + ct * 128 + c];
          sbuf[r * 132 + c] = f2b(diagl[n] * mv * acc[rf][cf][reg]);
          gbuf[r * 132 + c] = f2b(mv * acc[rf][2 + cf][reg]);
        }
      }
    }
  }
  __syncthreads();
  // phase 2: mixing. i,j uniform across threads -> aoff reads are broadcasts.
  const int d7   = tid & 127;
  const int half = tid >> 7;
  const float bi = bias[ct * 128 + d7];
  for (int gg = 0; gg < 2; ++gg) {
    int g = half * 2 + gg;           // batch-group within tile (0..3)
    int rbase = g * 17;
    float gr[17];
    #pragma unroll
    for (int j = 0; j < 17; ++j) gr[j] = b2f(gbuf[(rbase + j) * 132 + d7]);
    #pragma unroll
    for (int i = 0; i < 17; ++i) {
      float s = b2f(sbuf[(rbase + i) * 132 + d7]) + bi;
      #pragma unroll
      for (int j = 0; j < 17; ++j) s += aoff[i * 17 + j] * gr[j];
      out[((bt * 4 + g) * 17 + i) * 256 + ct * 128 + d7] = s;
    }
  }
}

extern "C" void kernel_launch(void* const* d_in, const int* in_sizes, int n_in,
                              void* d_out, int out_size, void* d_ws, size_t ws_size,
                              hipStream_t stream) {
  const float* x    = (const float*)d_in[0];
  const float* W    = (const float*)d_in[1];
  const float* M    = (const float*)d_in[2];
  const float* adj  = (const float*)d_in[3];
  const float* adj2 = (const float*)d_in[4];
  const float* bias = (const float*)d_in[5];
  float* out = (float*)d_out;
  short* Wt  = (short*)d_ws;   // 262144 B scratch for transposed bf16 weights

  prep_wt<<<128, 256, 0, stream>>>(W, Wt);
  fused_mgc<<<4096, 256, 0, stream>>>(x, Wt, M, adj, adj2, bias, out);
}